// Round 13
// baseline (342.617 us; speedup 1.0000x reference)
//
#include <hip/hip_runtime.h>
#include <hip/hip_bf16.h>
#include <cstdint>
#include <cstddef>

// MonolithicSSMLayer: y = (scan(sigmoid(log_A), x@Bw^T + Bb)) @ Cw^T + Cb
// B=8, T=2048, D=N=1024.
// R12b: byte-identical resubmit of R12 (round-12 bench died to the same
// "container failed twice" infra signature as round 4, which a resubmit
// cured). Analysis: at (512,2) the allocator capped gemm1 at 128 VGPRs and
// spilled (R9) -> empirically the 2nd launch_bounds arg acts as CUDA
// min-blocks/CU (2 blocks -> 4 waves/SIMD -> 512/4 = 128 cap). (512,1)
// -> 2 waves/SIMD -> cap 256: launchable and roomy for the ~164-reg fused
// kernel. grid1 == 256 blocks == 1/CU so no occupancy is sacrificed.
// gemm1 reads x fp32 directly (T14 async split: dwordx4 loads p0/p1,
// cvt+ds_write after the p3 vmcnt); cvt shrinks to weights-only (12 MB).
// gemm2 = R11-verified (operand-swap, plain f32x4 stores).

typedef __attribute__((ext_vector_type(8))) short short8;
typedef __attribute__((ext_vector_type(4))) short short4v;
typedef __attribute__((ext_vector_type(4))) float f32x4;

#define AS_GLOBAL(p) ((const __attribute__((address_space(1))) void*)(p))
#define AS_LDS(p)    ((__attribute__((address_space(3))) void*)(p))

__device__ __forceinline__ unsigned short f2bf(float f) {
    union { float f; unsigned u; } v; v.f = f;
    return (unsigned short)((v.u + 0x7FFFu + ((v.u >> 16) & 1u)) >> 16);
}
__device__ __forceinline__ float bf2f(unsigned short u) {
    union { float f; unsigned u; } v; v.u = ((unsigned)u) << 16;
    return v.f;
}

// ---------------- weights-only fp32 -> bf16 (fused path) ----------------
__global__ void cvt_w(const float4* __restrict__ bw, const float4* __restrict__ cw,
                      ushort4* __restrict__ bo, ushort4* __restrict__ co) {
    const int NW = (1024 * 1024) / 4;
    int i = blockIdx.x * blockDim.x + threadIdx.x;     // grid 2048*256 = 2*NW exact
    const float4* s; ushort4* d; int j;
    if (i < NW) { s = bw; d = bo; j = i; }
    else        { s = cw; d = co; j = i - NW; }
    float4 v = s[j];
    d[j] = make_ushort4(f2bf(v.x), f2bf(v.y), f2bf(v.z), f2bf(v.w));
}

// ---------------- full convert (fallback path only) ----------------
__global__ void cvt_all(const float4* __restrict__ x, const float4* __restrict__ bw,
                        const float4* __restrict__ cw, ushort4* __restrict__ xo,
                        ushort4* __restrict__ bo, ushort4* __restrict__ co) {
    const int NX = (16384 * 1024) / 4;
    const int NW = (1024 * 1024) / 4;
    int i = blockIdx.x * blockDim.x + threadIdx.x;
    int stride = gridDim.x * blockDim.x;
    for (; i < NX + 2 * NW; i += stride) {
        const float4* s; ushort4* d; int j;
        if (i < NX)           { s = x;  d = xo; j = i; }
        else if (i < NX + NW) { s = bw; d = bo; j = i - NX; }
        else                  { s = cw; d = co; j = i - NX - NW; }
        float4 v = s[j];
        d[j] = make_ushort4(f2bf(v.x), f2bf(v.y), f2bf(v.z), f2bf(v.w));
    }
}

// ---------------- GEMM1 (8-phase) + scan fused, fp32-A staging ----------------
// X = x fp32 [M,K], B = Bw bf16 [N,K] (NT), H out bf16 [M,N].
// Tile 256x256, BK=64, 512 thr / 8 waves (2Mx4N), wave tile 128x64.
// LDS: ldsA ring 4x16KB [0,64K), ldsB ring 4x16KB [64K,128K),
// ldsW ring 2x4KB [128K,136K); post-loop Sx[288][260] bf16 [0,149760).
// A/W staged via regs: fp32 loads issued p0/p1, cvt+ds_write at p3 after
// the per-tile vmcnt; B staged via global_load_lds (bf16 weights).
// Swizzle: logical byte l at row r -> physical l ^ ((r&7)<<4) (rule #21).
__global__ __launch_bounds__(512, 1)
void gemm1_8ph_scan(const float* __restrict__ X,
                    const unsigned short* __restrict__ B,
                    const float* __restrict__ bias,
                    const float* __restrict__ logA,
                    unsigned short* __restrict__ H,
                    int M, int N, int K)
{
    constexpr int NKT = 16;                      // K / 64
    constexpr int SXS = 260;                     // Sx row stride (elems)
    __shared__ __align__(16) char smem[149760];
    char* ldsA = smem;
    char* ldsB = smem + 65536;
    char* ldsW = smem + 131072;
    unsigned short* Sx = (unsigned short*)smem;

    const int tid  = threadIdx.x;
    const int lane = tid & 63;
    const int wave = tid >> 6;
    const int wg   = wave >> 2;                  // A half / warmup row-frag
    const int wm   = wg * 128;
    const int wn   = (wave & 3) * 64;
    const int hB   = wn >> 7;                    // B half this wave reads
    const int bR0  = wn & 127;                   // B row base within half
    const int q    = lane >> 4;
    const int l16  = lane & 15;
    const int swx  = (l16 & 7) << 4;
    const int m0   = blockIdx.x * 256;
    const int n0   = blockIdx.y * 256;

    // staging maps. Linear dest byte d; logical l = d ^ (((d>>7)&7)<<4);
    // element = (row l>>7, col (l&127)>>1) of the half-tile.
    const float*          aF[2];                 // fp32 x source
    const unsigned short* bSrc[2];               // bf16 weight source
    int dDst[2];
    #pragma unroll
    for (int p = 0; p < 2; ++p) {
        const int d = tid * 16 + p * 8192;
        const int l = d ^ (((d >> 7) & 7) << 4);
        const int srow = l >> 7;
        const int scol = (l & 127) >> 1;
        aF[p]   = X + (size_t)(m0 + srow) * K + scol;
        bSrc[p] = B + (size_t)(n0 + srow) * K + scol;
        dDst[p] = d;
    }
    // W: 4KB bf16 half-tile = 512 thr x 8B; fp32 source 16B/thread.
    const int dW  = tid * 8;
    const int lWb = dW ^ (((dW >> 7) & 7) << 4);
    int wrow = m0 - 32 + (lWb >> 7); if (wrow < 0) wrow = 0;  // bx==0 clamp
    const float* wF = X + (size_t)wrow * K + ((lWb & 127) >> 1);

    auto issueA = [&](int h, int kt, f32x4 (&ld)[2][2]) {
        #pragma unroll
        for (int c = 0; c < 2; ++c) {
            const float* s = aF[c] + (size_t)h * 128 * K + kt * 64;
            ld[c][0] = *reinterpret_cast<const f32x4*>(s);
            ld[c][1] = *reinterpret_cast<const f32x4*>(s + 4);
        }
    };
    auto writeA = [&](int h, int kt, const f32x4 (&ld)[2][2]) {
        const int slot = ((2 * kt + h) & 3) << 14;
        #pragma unroll
        for (int c = 0; c < 2; ++c) {
            short8 w;
            w[0] = (short)f2bf(ld[c][0][0]); w[1] = (short)f2bf(ld[c][0][1]);
            w[2] = (short)f2bf(ld[c][0][2]); w[3] = (short)f2bf(ld[c][0][3]);
            w[4] = (short)f2bf(ld[c][1][0]); w[5] = (short)f2bf(ld[c][1][1]);
            w[6] = (short)f2bf(ld[c][1][2]); w[7] = (short)f2bf(ld[c][1][3]);
            *reinterpret_cast<short8*>(ldsA + slot + dDst[c]) = w;
        }
    };
    auto issueW = [&](int kt, f32x4& ld) {
        ld = *reinterpret_cast<const f32x4*>(wF + kt * 64);
    };
    auto writeW = [&](int kt, const f32x4& ld) {
        const int slot = (kt & 1) << 12;
        short4v w;
        w[0] = (short)f2bf(ld[0]); w[1] = (short)f2bf(ld[1]);
        w[2] = (short)f2bf(ld[2]); w[3] = (short)f2bf(ld[3]);
        *reinterpret_cast<short4v*>(ldsW + slot + dW) = w;
    };
    auto stageB = [&](int h, int kt) {
        const int slot = ((2 * kt + h) & 3) << 14;
        #pragma unroll
        for (int p = 0; p < 2; ++p)
            __builtin_amdgcn_global_load_lds(
                AS_GLOBAL(bSrc[p] + (size_t)h * 128 * K + kt * 64),
                AS_LDS(ldsB + slot + dDst[p]), 16, 0, 0);
    };

    f32x4 acc[8][4] = {};
    f32x4 accw[4]   = {};
    f32x4 lA0[2][2], lA1[2][2], regW;

    // prologue. Ledger: 9 -> vmcnt(0) -> 0 -> 9+8=17 -> vmcnt(8) (tile1 A/W
    // done, B's 8 left) -> vmcnt(4) (B(0) done, B(1) left) -> lgkm -> bar.
    issueA(0, 0, lA0); issueA(1, 0, lA1); issueW(0, regW);
    asm volatile("s_waitcnt vmcnt(0)" ::: "memory");
    writeA(0, 0, lA0); writeA(1, 0, lA1); writeW(0, regW);
    issueA(0, 1, lA0); issueA(1, 1, lA1); issueW(1, regW);
    stageB(0, 0); stageB(1, 0); stageB(0, 1); stageB(1, 1);
    asm volatile("s_waitcnt vmcnt(8)" ::: "memory");
    writeA(0, 1, lA0); writeA(1, 1, lA1); writeW(1, regW);
    asm volatile("s_waitcnt vmcnt(4)" ::: "memory");
    asm volatile("s_waitcnt lgkmcnt(0)" ::: "memory");
    __builtin_amdgcn_s_barrier();

    #pragma unroll 1
    for (int kt = 0; kt < NKT; ++kt) {
        const int aSlot = ((2 * kt + wg) & 3) << 14;
        const int bSlot = ((2 * kt + hB) & 3) << 14;
        const int wSlot = (kt & 1) << 12;
        short8 bfrag[4][2];
        short8 aw[2];
        #pragma unroll
        for (int p = 0; p < 4; ++p) {
            short8 afrag[2][2];
            #pragma unroll
            for (int i2 = 0; i2 < 2; ++i2)
                #pragma unroll
                for (int ks = 0; ks < 2; ++ks) {
                    const int row = (p * 2 + i2) * 16 + l16;     // within half
                    const int lby = row * 128 + ks * 64 + q * 16;
                    afrag[i2][ks] = *reinterpret_cast<const short8*>(ldsA + aSlot + (lby ^ swx));
                }
            if (p == 0) {
                #pragma unroll
                for (int j = 0; j < 4; ++j)
                    #pragma unroll
                    for (int ks = 0; ks < 2; ++ks) {
                        const int row = bR0 + j * 16 + l16;
                        const int lby = row * 128 + ks * 64 + q * 16;
                        bfrag[j][ks] = *reinterpret_cast<const short8*>(ldsB + bSlot + (lby ^ swx));
                    }
                #pragma unroll
                for (int ks = 0; ks < 2; ++ks) {
                    const int row = wg * 16 + l16;               // warmup rows
                    const int lby = row * 128 + ks * 64 + q * 16;
                    aw[ks] = *reinterpret_cast<const short8*>(ldsW + wSlot + (lby ^ swx));
                }
            }
            // staging: A/W fp32 loads issued p0/p1; B gload_lds p2/p3;
            // cvt+ds_write of A/W after the p3 vmcnt (loads certified done).
            if (p == 0 && kt >= 1 && kt + 1 < NKT) issueA(0, kt + 1, lA0);
            if (p == 1 && kt >= 1 && kt + 1 < NKT) { issueA(1, kt + 1, lA1); issueW(kt + 1, regW); }
            if (p == 2 && kt + 2 < NKT) stageB(0, kt + 2);
            if (p == 3) {
                if (kt + 2 < NKT) stageB(1, kt + 2);
                if (kt < NKT - 2)       asm volatile("s_waitcnt vmcnt(4)" ::: "memory");
                else if (kt == NKT - 2) asm volatile("s_waitcnt vmcnt(0)" ::: "memory");
                if (kt >= 1 && kt + 1 < NKT) {
                    writeA(0, kt + 1, lA0); writeA(1, kt + 1, lA1); writeW(kt + 1, regW);
                }
            }
            __builtin_amdgcn_s_barrier();
            asm volatile("s_waitcnt lgkmcnt(0)" ::: "memory");
            __builtin_amdgcn_s_setprio(1);
            #pragma unroll
            for (int ks = 0; ks < 2; ++ks)
                #pragma unroll
                for (int i2 = 0; i2 < 2; ++i2)
                    #pragma unroll
                    for (int j = 0; j < 4; ++j)
                        acc[p * 2 + i2][j] = __builtin_amdgcn_mfma_f32_16x16x32_bf16(
                            afrag[i2][ks], bfrag[j][ks], acc[p * 2 + i2][j], 0, 0, 0);
            #pragma unroll
            for (int ks = 0; ks < 2; ++ks)
                accw[p] = __builtin_amdgcn_mfma_f32_16x16x32_bf16(
                    aw[ks], bfrag[p][ks], accw[p], 0, 0, 0);
            __builtin_amdgcn_s_setprio(0);
            __builtin_amdgcn_s_barrier();
        }
    }

    // ---- stage Bx tile (+bias) into Sx: rows 0..31 warmup, 32..287 main ----
    float bcol[4];
    #pragma unroll
    for (int j = 0; j < 4; ++j)
        bcol[j] = bias[n0 + wn + j * 16 + l16];

    #pragma unroll
    for (int j = 0; j < 4; ++j) {
        #pragma unroll
        for (int r = 0; r < 4; ++r)
            Sx[(wg * 16 + q * 4 + r) * SXS + wn + j * 16 + l16] = f2bf(accw[j][r] + bcol[j]);
        #pragma unroll
        for (int i = 0; i < 8; ++i)
            #pragma unroll
            for (int r = 0; r < 4; ++r)
                Sx[(32 + wm + i * 16 + q * 4 + r) * SXS + wn + j * 16 + l16] = f2bf(acc[i][j][r] + bcol[j]);
    }
    __syncthreads();

    // ---- scan: 2 threads/column, 128 t-steps each, 32-step warmup ----
    const int col  = tid & 255;
    const int half = tid >> 8;
    const int n    = n0 + col;
    const float Aa = 1.0f / (1.0f + __expf(-logA[n]));
    const bool chunk0 = (blockIdx.x & 7) == 0;   // t0 == 0 within batch

    float h = 0.0f;
    const int rw = half ? 128 : 0;               // Sx warmup rows
    if (!(half == 0 && chunk0)) {
        #pragma unroll
        for (int r = 0; r < 32; ++r)
            h = fmaf(Aa, h, bf2f(Sx[(rw + r) * SXS + col]));
    }
    const int rs = half ? 160 : 32;
    size_t o = (size_t)(m0 + (half ? 128 : 0)) * 1024 + n;
    #pragma unroll 8
    for (int r = 0; r < 128; ++r) {
        h = fmaf(Aa, h, bf2f(Sx[(rs + r) * SXS + col]));
        H[o] = f2bf(h);
        o += 1024;
    }
}

// ---------------- GEMM2: 256x256 / BK=64, faithful 8-phase (R11, verified) ----------------
// Operand-swapped MFMA -> lane l16 = m-row, q*4+reg = n-col -> 32x plain
// global_store_dwordx4 (L2 coalesces half-lines; NT was 1.26x write-amp).
__global__ __launch_bounds__(512, 2)
void gemm2_8ph(const unsigned short* __restrict__ A,
               const unsigned short* __restrict__ B,
               const float* __restrict__ bias,
               float* __restrict__ C,
               int M, int N, int K)
{
    constexpr int NKT = 16;                      // K / 64
    __shared__ __align__(16) unsigned short As[4 * 8192];     // 4 x 16 KB
    __shared__ __align__(16) unsigned short Bs[4 * 8192];     // 4 x 16 KB

    const int tid  = threadIdx.x;
    const int lane = tid & 63;
    const int wave = tid >> 6;
    const int wg   = wave >> 2;
    const int wm   = wg * 128;
    const int wn   = (wave & 3) * 64;
    const int hB   = wn >> 7;
    const int bR0  = wn & 127;
    const int q    = lane >> 4;
    const int l16  = lane & 15;
    const int swx  = (l16 & 7) << 4;
    const int m0   = blockIdx.x * 256;
    const int n0   = blockIdx.y * 256;

    const unsigned short* aSrc[2];
    const unsigned short* bSrc[2];
    int dDst[2];
    #pragma unroll
    for (int p = 0; p < 2; ++p) {
        const int d = tid * 16 + p * 8192;
        const int l = d ^ (((d >> 7) & 7) << 4);
        const int srow = l >> 7;
        const int scol = (l & 127) >> 1;
        aSrc[p] = A + (size_t)(m0 + srow) * K + scol;
        bSrc[p] = B + (size_t)(n0 + srow) * K + scol;
        dDst[p] = d;
    }

    char* ldsA = (char*)As;
    char* ldsB = (char*)Bs;

    auto stageA = [&](int h, int kt) {
        const int slot = ((2 * kt + h) & 3) << 14;
        #pragma unroll
        for (int p = 0; p < 2; ++p)
            __builtin_amdgcn_global_load_lds(
                AS_GLOBAL(aSrc[p] + (size_t)h * 128 * K + kt * 64),
                AS_LDS(ldsA + slot + dDst[p]), 16, 0, 0);
    };
    auto stageB = [&](int h, int kt) {
        const int slot = ((2 * kt + h) & 3) << 14;
        #pragma unroll
        for (int p = 0; p < 2; ++p)
            __builtin_amdgcn_global_load_lds(
                AS_GLOBAL(bSrc[p] + (size_t)h * 128 * K + kt * 64),
                AS_LDS(ldsB + slot + dDst[p]), 16, 0, 0);
    };

    f32x4 acc[8][4] = {};

    stageA(0, 0); stageA(1, 0); stageB(0, 0); stageB(1, 0);
    stageA(0, 1); stageA(1, 1); stageB(0, 1); stageB(1, 1);
    asm volatile("s_waitcnt vmcnt(8)" ::: "memory");
    __builtin_amdgcn_s_barrier();

    #pragma unroll 1
    for (int kt = 0; kt < NKT; ++kt) {
        const int aSlot = ((2 * kt + wg) & 3) << 14;
        const int bSlot = ((2 * kt + hB) & 3) << 14;
        short8 bfrag[4][2];
        #pragma unroll
        for (int p = 0; p < 4; ++p) {
            short8 afrag[2][2];
            #pragma unroll
            for (int i2 = 0; i2 < 2; ++i2)
                #pragma unroll
                for (int ks = 0; ks < 2; ++ks) {
                    const int row = (p * 2 + i2) * 16 + l16;
                    const int lby = row * 128 + ks * 64 + q * 16;
                    afrag[i2][ks] = *reinterpret_cast<const short8*>(ldsA + aSlot + (lby ^ swx));
                }
            if (p == 0) {
                #pragma unroll
                for (int j = 0; j < 4; ++j)
                    #pragma unroll
                    for (int ks = 0; ks < 2; ++ks) {
                        const int row = bR0 + j * 16 + l16;
                        const int lby = row * 128 + ks * 64 + q * 16;
                        bfrag[j][ks] = *reinterpret_cast<const short8*>(ldsB + bSlot + (lby ^ swx));
                    }
            }
            if (p == 0) { if (kt >= 1 && kt + 1 < NKT) stageA(0, kt + 1); }
            if (p == 1) { if (kt >= 1 && kt + 1 < NKT) stageA(1, kt + 1); }
            if (p == 2) { if (kt + 2 < NKT) stageB(0, kt + 2); }
            if (p == 3) {
                if (kt + 2 < NKT) stageB(1, kt + 2);
                if (kt < NKT - 2)       asm volatile("s_waitcnt vmcnt(4)" ::: "memory");
                else if (kt == NKT - 2) asm volatile("s_waitcnt vmcnt(0)" ::: "memory");
            }
            __builtin_amdgcn_s_barrier();
            asm volatile("s_waitcnt lgkmcnt(0)" ::: "memory");
            __builtin_amdgcn_s_setprio(1);
            // swapped operands (bfrag as A_op): lane l16 = m-row,
            // q*4+reg = n-col (legal: both frags share the NT layout).
            #pragma unroll
            for (int ks = 0; ks < 2; ++ks)
                #pragma unroll
                for (int i2 = 0; i2 < 2; ++i2)
                    #pragma unroll
                    for (int j = 0; j < 4; ++j)
                        acc[p * 2 + i2][j] = __builtin_amdgcn_mfma_f32_16x16x32_bf16(
                            bfrag[j][ks], afrag[i2][ks], acc[p * 2 + i2][j], 0, 0, 0);
            __builtin_amdgcn_s_setprio(0);
            __builtin_amdgcn_s_barrier();
        }
    }

    f32x4 bq[4];
    #pragma unroll
    for (int j = 0; j < 4; ++j)
        bq[j] = *reinterpret_cast<const f32x4*>(&bias[n0 + wn + j * 16 + q * 4]);

    #pragma unroll
    for (int i = 0; i < 8; ++i) {
        const int row = m0 + wm + i * 16 + l16;
        #pragma unroll
        for (int j = 0; j < 4; ++j) {
            const int col = n0 + wn + j * 16 + q * 4;
            f32x4 o = acc[i][j] + bq[j];
            *reinterpret_cast<f32x4*>(&C[(size_t)row * N + col]) = o;
        }
    }
}

// ---------------- standalone scan (fallback path only) ----------------
__global__ __launch_bounds__(256)
void ssm_scan(const float* __restrict__ Bx,
              const float* __restrict__ logA,
              unsigned short* __restrict__ H)
{
    constexpr int T = 2048, NS = 1024, L = 64, W = 32;
    const int tid   = threadIdx.x;
    const int bi    = blockIdx.x;
    const int ng    = bi & 3;
    const int chunk = (bi >> 2) & 31;
    const int b     = bi >> 7;
    const int n     = ng * 256 + tid;

    const float Aa = 1.0f / (1.0f + __expf(-logA[n]));
    const int t0 = chunk * L;
    int tw = t0 - W; if (tw < 0) tw = 0;

    const size_t base = (size_t)b * T * NS + n;
    float h = 0.0f;
    for (int t = tw; t < t0; ++t)
        h = fmaf(Aa, h, Bx[base + (size_t)t * NS]);

    const float* src = Bx + base + (size_t)t0 * NS;
    unsigned short* dst = H + base + (size_t)t0 * NS;
    #pragma unroll 8
    for (int t = 0; t < L; ++t) {
        h = fmaf(Aa, h, src[(size_t)t * NS]);
        dst[(size_t)t * NS] = f2bf(h);
    }
}

extern "C" void kernel_launch(void* const* d_in, const int* in_sizes, int n_in,
                              void* d_out, int out_size, void* d_ws, size_t ws_size,
                              hipStream_t stream)
{
    const float* x    = (const float*)d_in[0];
    const float* logA = (const float*)d_in[1];
    const float* Bw   = (const float*)d_in[2];
    const float* Bb   = (const float*)d_in[3];
    const float* Cw   = (const float*)d_in[4];
    const float* Cb   = (const float*)d_in[5];
    float* out = (float*)d_out;

    const int M = 8 * 2048, N = 1024, K = 1024;

    unsigned short* xh  = (unsigned short*)d_ws;     // 32 MiB x bf16 (fallback only)
    unsigned short* Bwb = xh + (size_t)M * K;        // 2 MiB
    unsigned short* Cwb = Bwb + (size_t)N * K;       // 2 MiB
    unsigned short* hb  = Cwb + (size_t)N * K;       // 32 MiB h bf16 (fused path)

    const size_t need_fused = ((size_t)M * K * 2 + (size_t)N * K * 2) * 2 + (size_t)N * K * 2;

    dim3 grid1(M / 256, N / 256);
    dim3 grid2(M / 256, N / 256);
    if (ws_size >= need_fused) {
        cvt_w<<<2048, 256, 0, stream>>>((const float4*)Bw, (const float4*)Cw,
                                        (ushort4*)Bwb, (ushort4*)Cwb);
        gemm1_8ph_scan<<<grid1, 512, 0, stream>>>(x, Bwb, Bb, logA, hb, M, N, K);
        gemm2_8ph<<<grid2, 512, 0, stream>>>(hb, Cwb, Cb, out, M, N, K);
    } else {
        cvt_all<<<4096, 256, 0, stream>>>((const float4*)x, (const float4*)Bw,
                                          (const float4*)Cw, (ushort4*)xh,
                                          (ushort4*)Bwb, (ushort4*)Cwb);
        gemm2_8ph<<<grid2, 512, 0, stream>>>(xh, Bwb, Bb, out, M, N, K);
        ssm_scan<<<1024, 256, 0, stream>>>(out, logA, xh);
        gemm2_8ph<<<grid2, 512, 0, stream>>>(xh, Cwb, Cb, out, M, N, K);
    }
}

// Round 14
// 202.661 us; speedup vs baseline: 1.6906x; 1.6906x over previous
//
#include <hip/hip_runtime.h>
#include <hip/hip_bf16.h>
#include <cstdint>
#include <cstddef>

// MonolithicSSMLayer: y = (scan(sigmoid(log_A), x@Bw^T + Bb)) @ Cw^T + Cb
// B=8, T=2048, D=N=1024.
// R13: byte-identical revert to R11 (best verified: 202.7us).
// R12/R12b closed the x-fp32 fused-staging path permanently: the compiler
// pins 128 VGPRs for this 512-thread kernel regardless of launch_bounds
// (measured twice), so the 36-reg in-flight staging block spills to
// scratch (120MB phantom WRITE, MfmaUtil 7%, 4x). Composition:
// - cvt_all: x+Bw+Cw fp32->bf16 (verified streaming kernel).
// - gemm1_8ph_scan (R7b): 8-phase 256x256/BK=64, gload_lds bf16 staging,
//   4-slot half-tile ring + W warmup ring, vmcnt(4) steady checkpoint,
//   (row&7)<<4 swizzle, fused 288-row in-LDS scan. 0 bank conflicts,
//   FETCH 26.7MB, WRITE 32MB.
// - gemm2_8ph (R11): same schedule + operand-swapped MFMA (lane l16 =
//   m-row, q*4+reg = n-col) -> 32x plain f32x4 stores (NT hint removed:
//   it caused 1.26x write amplification via half-line HBM writes).

typedef __attribute__((ext_vector_type(8))) short short8;
typedef __attribute__((ext_vector_type(4))) float f32x4;

#define AS_GLOBAL(p) ((const __attribute__((address_space(1))) void*)(p))
#define AS_LDS(p)    ((__attribute__((address_space(3))) void*)(p))

__device__ __forceinline__ unsigned short f2bf(float f) {
    union { float f; unsigned u; } v; v.f = f;
    return (unsigned short)((v.u + 0x7FFFu + ((v.u >> 16) & 1u)) >> 16);
}
__device__ __forceinline__ float bf2f(unsigned short u) {
    union { float f; unsigned u; } v; v.u = ((unsigned)u) << 16;
    return v.f;
}

// ---------------- fused fp32 -> bf16 convert for x, B_w, C_w ----------------
__global__ void cvt_all(const float4* __restrict__ x, const float4* __restrict__ bw,
                        const float4* __restrict__ cw, ushort4* __restrict__ xo,
                        ushort4* __restrict__ bo, ushort4* __restrict__ co) {
    const int NX = (16384 * 1024) / 4;
    const int NW = (1024 * 1024) / 4;
    int i = blockIdx.x * blockDim.x + threadIdx.x;
    int stride = gridDim.x * blockDim.x;
    for (; i < NX + 2 * NW; i += stride) {
        const float4* s; ushort4* d; int j;
        if (i < NX)           { s = x;  d = xo; j = i; }
        else if (i < NX + NW) { s = bw; d = bo; j = i - NX; }
        else                  { s = cw; d = co; j = i - NX - NW; }
        float4 v = s[j];
        d[j] = make_ushort4(f2bf(v.x), f2bf(v.y), f2bf(v.z), f2bf(v.w));
    }
}

// ---------------- GEMM1 (8-phase) + scan fused (R7b, verified) ----------------
// A = x bf16 [M,K], B = Bw bf16 [N,K] (NT), H out bf16 [M,N].
// Tile 256x256, BK=64, 512 thr / 8 waves (2Mx4N), wave tile 128x64.
// LDS map: ldsA ring 4x16KB [0,64K), ldsB ring 4x16KB [64K,128K),
// ldsW ring 2x4KB [128K,136K); post-loop Sx[288][260] bf16 [0,149760).
// Warmup rows m0-32..m0-1 (clamped at m0==0; scan skips them at chunk0).
// Swizzle: logical byte l at row r -> physical l ^ ((r&7)<<4); linear
// gload_lds dest + pre-swizzled source; reads XOR (l16&7)<<4 (rule #21).
__global__ __launch_bounds__(512, 2)
void gemm1_8ph_scan(const unsigned short* __restrict__ A,
                    const unsigned short* __restrict__ B,
                    const float* __restrict__ bias,
                    const float* __restrict__ logA,
                    unsigned short* __restrict__ H,
                    int M, int N, int K)
{
    constexpr int NKT = 16;                      // K / 64
    constexpr int SXS = 260;                     // Sx row stride (elems)
    __shared__ __align__(16) char smem[149760];
    char* ldsA = smem;
    char* ldsB = smem + 65536;
    char* ldsW = smem + 131072;
    unsigned short* Sx = (unsigned short*)smem;

    const int tid  = threadIdx.x;
    const int lane = tid & 63;
    const int wave = tid >> 6;
    const int wg   = wave >> 2;                  // A half / warmup row-frag
    const int wm   = wg * 128;
    const int wn   = (wave & 3) * 64;
    const int hB   = wn >> 7;                    // B half this wave reads
    const int bR0  = wn & 127;                   // B row base within half
    const int q    = lane >> 4;
    const int l16  = lane & 15;
    const int swx  = (l16 & 7) << 4;
    const int m0   = blockIdx.x * 256;
    const int n0   = blockIdx.y * 256;

    // A/B staging maps: 2 x 16B gload_lds per half-tile per thread.
    const unsigned short* aSrc[2];
    const unsigned short* bSrc[2];
    int dDst[2];
    #pragma unroll
    for (int p = 0; p < 2; ++p) {
        const int d = tid * 16 + p * 8192;
        const int l = d ^ (((d >> 7) & 7) << 4);
        const int srow = l >> 7;
        const int scol = (l & 127) >> 1;
        aSrc[p] = A + (size_t)(m0 + srow) * K + scol;
        bSrc[p] = B + (size_t)(n0 + srow) * K + scol;
        dDst[p] = d;
    }
    // W staging map: 4KB half-tile, 1 inst/wave (lanes<32), dest wave*512+lane*16.
    const int dW = wave * 512 + lane * 16;
    const int lW = dW ^ (((dW >> 7) & 7) << 4);
    int wrow = m0 - 32 + (lW >> 7); if (wrow < 0) wrow = 0;   // bx==0 clamp
    const unsigned short* wSrc = A + (size_t)wrow * K + ((lW & 127) >> 1);

    auto stageA = [&](int h, int kt) {
        const int slot = ((2 * kt + h) & 3) << 14;
        #pragma unroll
        for (int p = 0; p < 2; ++p)
            __builtin_amdgcn_global_load_lds(
                AS_GLOBAL(aSrc[p] + (size_t)h * 128 * K + kt * 64),
                AS_LDS(ldsA + slot + dDst[p]), 16, 0, 0);
    };
    auto stageB = [&](int h, int kt) {
        const int slot = ((2 * kt + h) & 3) << 14;
        #pragma unroll
        for (int p = 0; p < 2; ++p)
            __builtin_amdgcn_global_load_lds(
                AS_GLOBAL(bSrc[p] + (size_t)h * 128 * K + kt * 64),
                AS_LDS(ldsB + slot + dDst[p]), 16, 0, 0);
    };
    auto stageW = [&](int kt) {
        if (lane < 32)
            __builtin_amdgcn_global_load_lds(
                AS_GLOBAL(wSrc + kt * 64),
                AS_LDS(ldsW + ((kt & 1) << 12) + dW), 16, 0, 0);
    };

    f32x4 acc[8][4] = {};
    f32x4 accw[4]   = {};

    // prologue: tiles 0,1 fully (9 inst each); wait tile 0 (oldest 9).
    stageA(0, 0); stageA(1, 0); stageW(0); stageB(0, 0); stageB(1, 0);
    stageA(0, 1); stageA(1, 1); stageW(1); stageB(0, 1); stageB(1, 1);
    asm volatile("s_waitcnt vmcnt(9)" ::: "memory");
    __builtin_amdgcn_s_barrier();

    #pragma unroll 1
    for (int kt = 0; kt < NKT; ++kt) {
        const int aSlot = ((2 * kt + wg) & 3) << 14;
        const int bSlot = ((2 * kt + hB) & 3) << 14;
        const int wSlot = (kt & 1) << 12;
        short8 bfrag[4][2];
        short8 aw[2];
        #pragma unroll
        for (int p = 0; p < 4; ++p) {
            short8 afrag[2][2];
            #pragma unroll
            for (int i2 = 0; i2 < 2; ++i2)
                #pragma unroll
                for (int ks = 0; ks < 2; ++ks) {
                    const int row = (p * 2 + i2) * 16 + l16;     // within half
                    const int lby = row * 128 + ks * 64 + q * 16;
                    afrag[i2][ks] = *reinterpret_cast<const short8*>(ldsA + aSlot + (lby ^ swx));
                }
            if (p == 0) {
                #pragma unroll
                for (int j = 0; j < 4; ++j)
                    #pragma unroll
                    for (int ks = 0; ks < 2; ++ks) {
                        const int row = bR0 + j * 16 + l16;
                        const int lby = row * 128 + ks * 64 + q * 16;
                        bfrag[j][ks] = *reinterpret_cast<const short8*>(ldsB + bSlot + (lby ^ swx));
                    }
                #pragma unroll
                for (int ks = 0; ks < 2; ++ks) {
                    const int row = wg * 16 + l16;               // warmup rows
                    const int lby = row * 128 + ks * 64 + q * 16;
                    aw[ks] = *reinterpret_cast<const short8*>(ldsW + wSlot + (lby ^ swx));
                }
            }
            // fine-interleaved staging: one half-tile (+W at p0) per phase
            if (p == 0 && kt >= 1 && kt + 1 < NKT) { stageA(0, kt + 1); stageW(kt + 1); }
            if (p == 1 && kt >= 1 && kt + 1 < NKT) stageA(1, kt + 1);
            if (p == 2 && kt + 2 < NKT) stageB(0, kt + 2);
            if (p == 3) {
                if (kt + 2 < NKT) stageB(1, kt + 2);
                if (kt < NKT - 2)       asm volatile("s_waitcnt vmcnt(4)" ::: "memory");
                else if (kt == NKT - 2) asm volatile("s_waitcnt vmcnt(0)" ::: "memory");
            }
            __builtin_amdgcn_s_barrier();
            asm volatile("s_waitcnt lgkmcnt(0)" ::: "memory");
            __builtin_amdgcn_s_setprio(1);
            #pragma unroll
            for (int ks = 0; ks < 2; ++ks)
                #pragma unroll
                for (int i2 = 0; i2 < 2; ++i2)
                    #pragma unroll
                    for (int j = 0; j < 4; ++j)
                        acc[p * 2 + i2][j] = __builtin_amdgcn_mfma_f32_16x16x32_bf16(
                            afrag[i2][ks], bfrag[j][ks], acc[p * 2 + i2][j], 0, 0, 0);
            #pragma unroll
            for (int ks = 0; ks < 2; ++ks)
                accw[p] = __builtin_amdgcn_mfma_f32_16x16x32_bf16(
                    aw[ks], bfrag[p][ks], accw[p], 0, 0, 0);
            __builtin_amdgcn_s_setprio(0);
            __builtin_amdgcn_s_barrier();
        }
    }

    // ---- stage Bx tile (+bias) into Sx: rows 0..31 warmup, 32..287 main ----
    float bcol[4];
    #pragma unroll
    for (int j = 0; j < 4; ++j)
        bcol[j] = bias[n0 + wn + j * 16 + l16];

    #pragma unroll
    for (int j = 0; j < 4; ++j) {
        #pragma unroll
        for (int r = 0; r < 4; ++r)
            Sx[(wg * 16 + q * 4 + r) * SXS + wn + j * 16 + l16] = f2bf(accw[j][r] + bcol[j]);
        #pragma unroll
        for (int i = 0; i < 8; ++i)
            #pragma unroll
            for (int r = 0; r < 4; ++r)
                Sx[(32 + wm + i * 16 + q * 4 + r) * SXS + wn + j * 16 + l16] = f2bf(acc[i][j][r] + bcol[j]);
    }
    __syncthreads();

    // ---- scan: 2 threads/column, 128 t-steps each, 32-step warmup ----
    const int col  = tid & 255;
    const int half = tid >> 8;
    const int n    = n0 + col;
    const float Aa = 1.0f / (1.0f + __expf(-logA[n]));
    const bool chunk0 = (blockIdx.x & 7) == 0;   // t0 == 0 within batch

    float h = 0.0f;
    const int rw = half ? 128 : 0;               // Sx warmup rows
    if (!(half == 0 && chunk0)) {
        #pragma unroll
        for (int r = 0; r < 32; ++r)
            h = fmaf(Aa, h, bf2f(Sx[(rw + r) * SXS + col]));
    }
    const int rs = half ? 160 : 32;
    size_t o = (size_t)(m0 + (half ? 128 : 0)) * 1024 + n;
    #pragma unroll 8
    for (int r = 0; r < 128; ++r) {
        h = fmaf(Aa, h, bf2f(Sx[(rs + r) * SXS + col]));
        H[o] = f2bf(h);
        o += 1024;
    }
}

// ---------------- GEMM2: 256x256 / BK=64, faithful 8-phase (R11, verified) ----------------
// Operand-swapped MFMA -> lane l16 = m-row, q*4+reg = n-col -> 32x plain
// global_store_dwordx4 (L2 coalesces half-lines; NT was 1.26x write-amp).
__global__ __launch_bounds__(512, 2)
void gemm2_8ph(const unsigned short* __restrict__ A,
               const unsigned short* __restrict__ B,
               const float* __restrict__ bias,
               float* __restrict__ C,
               int M, int N, int K)
{
    constexpr int NKT = 16;                      // K / 64
    __shared__ __align__(16) unsigned short As[4 * 8192];     // 4 x 16 KB
    __shared__ __align__(16) unsigned short Bs[4 * 8192];     // 4 x 16 KB

    const int tid  = threadIdx.x;
    const int lane = tid & 63;
    const int wave = tid >> 6;
    const int wg   = wave >> 2;
    const int wm   = wg * 128;
    const int wn   = (wave & 3) * 64;
    const int hB   = wn >> 7;
    const int bR0  = wn & 127;
    const int q    = lane >> 4;
    const int l16  = lane & 15;
    const int swx  = (l16 & 7) << 4;
    const int m0   = blockIdx.x * 256;
    const int n0   = blockIdx.y * 256;

    const unsigned short* aSrc[2];
    const unsigned short* bSrc[2];
    int dDst[2];
    #pragma unroll
    for (int p = 0; p < 2; ++p) {
        const int d = tid * 16 + p * 8192;
        const int l = d ^ (((d >> 7) & 7) << 4);
        const int srow = l >> 7;
        const int scol = (l & 127) >> 1;
        aSrc[p] = A + (size_t)(m0 + srow) * K + scol;
        bSrc[p] = B + (size_t)(n0 + srow) * K + scol;
        dDst[p] = d;
    }

    char* ldsA = (char*)As;
    char* ldsB = (char*)Bs;

    auto stageA = [&](int h, int kt) {
        const int slot = ((2 * kt + h) & 3) << 14;
        #pragma unroll
        for (int p = 0; p < 2; ++p)
            __builtin_amdgcn_global_load_lds(
                AS_GLOBAL(aSrc[p] + (size_t)h * 128 * K + kt * 64),
                AS_LDS(ldsA + slot + dDst[p]), 16, 0, 0);
    };
    auto stageB = [&](int h, int kt) {
        const int slot = ((2 * kt + h) & 3) << 14;
        #pragma unroll
        for (int p = 0; p < 2; ++p)
            __builtin_amdgcn_global_load_lds(
                AS_GLOBAL(bSrc[p] + (size_t)h * 128 * K + kt * 64),
                AS_LDS(ldsB + slot + dDst[p]), 16, 0, 0);
    };

    f32x4 acc[8][4] = {};

    stageA(0, 0); stageA(1, 0); stageB(0, 0); stageB(1, 0);
    stageA(0, 1); stageA(1, 1); stageB(0, 1); stageB(1, 1);
    asm volatile("s_waitcnt vmcnt(8)" ::: "memory");
    __builtin_amdgcn_s_barrier();

    #pragma unroll 1
    for (int kt = 0; kt < NKT; ++kt) {
        const int aSlot = ((2 * kt + wg) & 3) << 14;
        const int bSlot = ((2 * kt + hB) & 3) << 14;
        short8 bfrag[4][2];
        #pragma unroll
        for (int p = 0; p < 4; ++p) {
            short8 afrag[2][2];
            #pragma unroll
            for (int i2 = 0; i2 < 2; ++i2)
                #pragma unroll
                for (int ks = 0; ks < 2; ++ks) {
                    const int row = (p * 2 + i2) * 16 + l16;
                    const int lby = row * 128 + ks * 64 + q * 16;
                    afrag[i2][ks] = *reinterpret_cast<const short8*>(ldsA + aSlot + (lby ^ swx));
                }
            if (p == 0) {
                #pragma unroll
                for (int j = 0; j < 4; ++j)
                    #pragma unroll
                    for (int ks = 0; ks < 2; ++ks) {
                        const int row = bR0 + j * 16 + l16;
                        const int lby = row * 128 + ks * 64 + q * 16;
                        bfrag[j][ks] = *reinterpret_cast<const short8*>(ldsB + bSlot + (lby ^ swx));
                    }
            }
            if (p == 0) { if (kt >= 1 && kt + 1 < NKT) stageA(0, kt + 1); }
            if (p == 1) { if (kt >= 1 && kt + 1 < NKT) stageA(1, kt + 1); }
            if (p == 2) { if (kt + 2 < NKT) stageB(0, kt + 2); }
            if (p == 3) {
                if (kt + 2 < NKT) stageB(1, kt + 2);
                if (kt < NKT - 2)       asm volatile("s_waitcnt vmcnt(4)" ::: "memory");
                else if (kt == NKT - 2) asm volatile("s_waitcnt vmcnt(0)" ::: "memory");
            }
            __builtin_amdgcn_s_barrier();
            asm volatile("s_waitcnt lgkmcnt(0)" ::: "memory");
            __builtin_amdgcn_s_setprio(1);
            // swapped operands (bfrag as A_op): lane l16 = m-row,
            // q*4+reg = n-col (legal: both frags share the NT layout).
            #pragma unroll
            for (int ks = 0; ks < 2; ++ks)
                #pragma unroll
                for (int i2 = 0; i2 < 2; ++i2)
                    #pragma unroll
                    for (int j = 0; j < 4; ++j)
                        acc[p * 2 + i2][j] = __builtin_amdgcn_mfma_f32_16x16x32_bf16(
                            bfrag[j][ks], afrag[i2][ks], acc[p * 2 + i2][j], 0, 0, 0);
            __builtin_amdgcn_s_setprio(0);
            __builtin_amdgcn_s_barrier();
        }
    }

    f32x4 bq[4];
    #pragma unroll
    for (int j = 0; j < 4; ++j)
        bq[j] = *reinterpret_cast<const f32x4*>(&bias[n0 + wn + j * 16 + q * 4]);

    #pragma unroll
    for (int i = 0; i < 8; ++i) {
        const int row = m0 + wm + i * 16 + l16;
        #pragma unroll
        for (int j = 0; j < 4; ++j) {
            const int col = n0 + wn + j * 16 + q * 4;
            f32x4 o = acc[i][j] + bq[j];
            *reinterpret_cast<f32x4*>(&C[(size_t)row * N + col]) = o;
        }
    }
}

// ---------------- standalone scan (fallback path only) ----------------
__global__ __launch_bounds__(256)
void ssm_scan(const float* __restrict__ Bx,
              const float* __restrict__ logA,
              unsigned short* __restrict__ H)
{
    constexpr int T = 2048, NS = 1024, L = 64, W = 32;
    const int tid   = threadIdx.x;
    const int bi    = blockIdx.x;
    const int ng    = bi & 3;
    const int chunk = (bi >> 2) & 31;
    const int b     = bi >> 7;
    const int n     = ng * 256 + tid;

    const float Aa = 1.0f / (1.0f + __expf(-logA[n]));
    const int t0 = chunk * L;
    int tw = t0 - W; if (tw < 0) tw = 0;

    const size_t base = (size_t)b * T * NS + n;
    float h = 0.0f;
    for (int t = tw; t < t0; ++t)
        h = fmaf(Aa, h, Bx[base + (size_t)t * NS]);

    const float* src = Bx + base + (size_t)t0 * NS;
    unsigned short* dst = H + base + (size_t)t0 * NS;
    #pragma unroll 8
    for (int t = 0; t < L; ++t) {
        h = fmaf(Aa, h, src[(size_t)t * NS]);
        dst[(size_t)t * NS] = f2bf(h);
    }
}

extern "C" void kernel_launch(void* const* d_in, const int* in_sizes, int n_in,
                              void* d_out, int out_size, void* d_ws, size_t ws_size,
                              hipStream_t stream)
{
    const float* x    = (const float*)d_in[0];
    const float* logA = (const float*)d_in[1];
    const float* Bw   = (const float*)d_in[2];
    const float* Bb   = (const float*)d_in[3];
    const float* Cw   = (const float*)d_in[4];
    const float* Cb   = (const float*)d_in[5];
    float* out = (float*)d_out;

    const int M = 8 * 2048, N = 1024, K = 1024;

    unsigned short* xh  = (unsigned short*)d_ws;     // 32 MiB x bf16
    unsigned short* Bwb = xh + (size_t)M * K;        // 2 MiB
    unsigned short* Cwb = Bwb + (size_t)N * K;       // 2 MiB
    unsigned short* hb  = Cwb + (size_t)N * K;       // 32 MiB h bf16 (fused path)

    const size_t need_fused = ((size_t)M * K * 2 + (size_t)N * K * 2) * 2 + (size_t)N * K * 2;

    cvt_all<<<4096, 256, 0, stream>>>((const float4*)x, (const float4*)Bw,
                                      (const float4*)Cw, (ushort4*)xh,
                                      (ushort4*)Bwb, (ushort4*)Cwb);

    dim3 grid1(M / 256, N / 256);
    dim3 grid2(M / 256, N / 256);
    if (ws_size >= need_fused) {
        gemm1_8ph_scan<<<grid1, 512, 0, stream>>>(xh, Bwb, Bb, logA, hb, M, N, K);
        gemm2_8ph<<<grid2, 512, 0, stream>>>(hb, Cwb, Cb, out, M, N, K);
    } else {
        gemm2_8ph<<<grid2, 512, 0, stream>>>(xh, Bwb, Bb, out, M, N, K);
        ssm_scan<<<1024, 256, 0, stream>>>(out, logA, xh);
        gemm2_8ph<<<grid2, 512, 0, stream>>>(xh, Cwb, Cb, out, M, N, K);
    }
}